// Round 10
// baseline (578.436 us; speedup 1.0000x reference)
//
#include <hip/hip_runtime.h>

// PiNet2 fused, MFMA f16 + CSR-ordered pairs, segmented flush.
// N_ATOMS=20000, N_PAIRS=640000, C=64, NB=4.
//
// k_pairs_s: 256-thread blocks (4 waves -> good residency per workgroup
// slot) but NO __syncthreads: each wave owns xpose[wv] exclusively, and
// same-wave LDS write->read ordering is enforced by lgkmcnt. Waves stay
// fully decoupled (r9) while filling the CU's workgroup slots (r8).
// 16 pairs per wave in CSR (sorted-by-atom-i) order; segment sums are
// run-length accumulated and flushed as ~1.5 atomicAdd rows per wave.
// Orientation: A = W^T (M=outch), B = activations^T (N=pairs).
// C/D layout (HW-verified): col = lane&15 (pair), row = (lane>>4)*4 + reg.
// Weights pre-packed (k_pack) into fragment-linear f16 with per-stage k-maps
// chosen so every stage->stage handoff is lane-local.

typedef _Float16 half8 __attribute__((ext_vector_type(8)));
typedef __fp16 half2t __attribute__((ext_vector_type(2)));   // cvt_pkrtz return type
typedef float floatx4 __attribute__((ext_vector_type(4)));

#define MFMA16(a, b, c) __builtin_amdgcn_mfma_f32_16x16x32_f16((a), (b), (c), 0, 0, 0)

// ws layout (bytes)
#define WSA_OFF 0            // 96 frags * 512 f16 * 2B = 98304
#define W3_OFF 98304
#define P1H_OFF 114688       // 20000*64 f16
#define P3H_OFF 2674688      // 20000*192 f16
#define CNT_OFF 10354688     // 20224 ints
#define FILL_OFF 10435584    // 20224 ints
#define OFF_OFF 10516480     // 20224 ints
#define BSUM_OFF 10597376    // 128 ints
#define IIS_OFF 13157888     // 640000 ints (atom i of slot)
#define JJS_OFF 15717888     // 640000 ints (atom j of slot)
#define BAS_OFF 18277888     // 640000 float4
#define DIF_OFF 28517888     // 640000 float4 (xyz + pad)  -> end 38757888

// frag-table bases (in frag units, 512 f16 each)
#define FB_PI1 0
#define FB_PI2 16
#define FB_II1 48
#define FB_II2 56
#define FB_PXI 80
#define FB_PXJ 88

__device__ __forceinline__ float fast_tanh(float x) {
    float t = __expf(2.0f * x);
    return 1.0f - __fdividef(2.0f, t + 1.0f);
}

__device__ __forceinline__ floatx4 tanh4(floatx4 v) {
    floatx4 r;
    r[0] = fast_tanh(v[0]); r[1] = fast_tanh(v[1]);
    r[2] = fast_tanh(v[2]); r[3] = fast_tanh(v[3]);
    return r;
}

__device__ __forceinline__ void pack_can(const floatx4 h[4], half8& lo, half8& hi) {
    half2t dw[8];
#pragma unroll
    for (int t = 0; t < 4; ++t) {
        dw[2 * t]     = __builtin_amdgcn_cvt_pkrtz(h[t][0], h[t][1]);
        dw[2 * t + 1] = __builtin_amdgcn_cvt_pkrtz(h[t][2], h[t][3]);
    }
    union U { half8 v; half2t d[4]; } u;
    u.d[0] = dw[0]; u.d[1] = dw[1]; u.d[2] = dw[2]; u.d[3] = dw[3]; lo = u.v;
    u.d[0] = dw[4]; u.d[1] = dw[5]; u.d[2] = dw[6]; u.d[3] = dw[7]; hi = u.v;
}

// ---------------- weight pre-pack ----------------
__global__ __launch_bounds__(64) void k_pack(
    const float* __restrict__ Wpi1, const float* __restrict__ Wpi2,
    const float* __restrict__ Wii1, const float* __restrict__ Wii2,
    const float* __restrict__ Wpxi, const float* __restrict__ Wpxj,
    _Float16* __restrict__ wsA) {
    int f = blockIdx.x, l = threadIdx.x;
    int q = l >> 4, c15 = l & 15;
    const float* W; int ldn, mt, kb, mode;
    if (f < 16)      { W = Wpi1; ldn = 64;  mt = f >> 2;        kb = f & 3;        mode = 0; }
    else if (f < 48) { W = Wpi2; ldn = 256; mt = (f - 16) >> 1; kb = (f - 16) & 1; mode = 1; }
    else if (f < 56) { W = Wii1; ldn = 64;  mt = (f - 48) >> 1; kb = (f - 48) & 1; mode = 2; }
    else if (f < 80) { W = Wii2; ldn = 192; mt = (f - 56) >> 1; kb = (f - 56) & 1; mode = 1; }
    else if (f < 88) { W = Wpxi; ldn = 64;  mt = (f - 80) >> 1; kb = (f - 80) & 1; mode = 0; }
    else             { W = Wpxj; ldn = 64;  mt = (f - 88) >> 1; kb = (f - 88) & 1; mode = 0; }
#pragma unroll
    for (int e = 0; e < 8; ++e) {
        int k;
        if (mode == 0) k = 32 * kb + 8 * q + e;
        else if (mode == 1) {
            int d = e >> 1, h = e & 1, j = 4 * kb + d;
            k = 16 * (j >> 1) + 4 * q + 2 * (j & 1) + h;
        } else k = 4 * (8 * kb + e) + q;
        wsA[f * 512 + l * 8 + e] = (_Float16)W[k * ldn + 16 * mt + c15];
    }
}

// ---------------- K0: W3 = Wpp3a @ Wpp3b ----------------
__global__ __launch_bounds__(256) void k_w3(const float* __restrict__ A,
                                            const float* __restrict__ B,
                                            float* __restrict__ W3) {
    int t = threadIdx.x;
#pragma unroll
    for (int e = 0; e < 16; ++e) {
        int idx = t * 16 + e;
        int k = idx >> 6, c = idx & 63;
        float s = 0.f;
        for (int m = 0; m < 64; ++m) s = fmaf(A[k * 64 + m], B[m * 64 + c], s);
        W3[idx] = s;
    }
}

__device__ __forceinline__ void store8(float* dst, const float v[8]) {
    *(float4*)(dst)     = make_float4(v[0], v[1], v[2], v[3]);
    *(float4*)(dst + 4) = make_float4(v[4], v[5], v[6], v[7]);
}
__device__ __forceinline__ void fma8(const float* row, float wv, float acc[8]) {
    float4 x0 = *(const float4*)(row);
    float4 x1 = *(const float4*)(row + 4);
    acc[0] = fmaf(x0.x, wv, acc[0]); acc[1] = fmaf(x0.y, wv, acc[1]);
    acc[2] = fmaf(x0.z, wv, acc[2]); acc[3] = fmaf(x0.w, wv, acc[3]);
    acc[4] = fmaf(x1.x, wv, acc[4]); acc[5] = fmaf(x1.y, wv, acc[5]);
    acc[6] = fmaf(x1.z, wv, acc[6]); acc[7] = fmaf(x1.w, wv, acc[7]);
}

// ---------------- K1: p1h (f16 out) ----------------
__global__ __launch_bounds__(256) void k_p1h(const float* __restrict__ p1,
                                             const float* __restrict__ Wa,
                                             const float* __restrict__ ba,
                                             const float* __restrict__ Wb,
                                             const float* __restrict__ bb,
                                             _Float16* __restrict__ p1h) {
    __shared__ float act[4][64][8];
    const int w = threadIdx.x >> 6, lane = threadIdx.x & 63;
    const int a0 = blockIdx.x * 32 + w * 8;
    {
        float t[8];
#pragma unroll
        for (int p = 0; p < 8; ++p) t[p] = p1[(a0 + p) * 64 + lane];
        store8(&act[w][lane][0], t);
    }
    __syncthreads();
    float acc[8];
    {
        float bv = ba[lane];
#pragma unroll
        for (int p = 0; p < 8; ++p) acc[p] = bv;
        for (int k = 0; k < 64; ++k) fma8(&act[w][k][0], Wa[k * 64 + lane], acc);
    }
    __syncthreads();
    {
        float t[8];
#pragma unroll
        for (int p = 0; p < 8; ++p) t[p] = fast_tanh(acc[p]);
        store8(&act[w][lane][0], t);
    }
    __syncthreads();
    {
        float bv = bb[lane];
#pragma unroll
        for (int p = 0; p < 8; ++p) acc[p] = bv;
        for (int k = 0; k < 64; ++k) fma8(&act[w][k][0], Wb[k * 64 + lane], acc);
    }
#pragma unroll
    for (int p = 0; p < 8; ++p) p1h[(a0 + p) * 64 + lane] = (_Float16)fast_tanh(acc[p]);
}

// ---------------- K2: p3h = p3 @ W3 (f16 out) ----------------
__global__ __launch_bounds__(256) void k_rowmm(const float* __restrict__ X,
                                               const float* __restrict__ W,
                                               _Float16* __restrict__ Y) {
    __shared__ float act[4][64][8];
    const int w = threadIdx.x >> 6, lane = threadIdx.x & 63;
    const int r0 = blockIdx.x * 32 + w * 8;
    {
        float t[8];
#pragma unroll
        for (int p = 0; p < 8; ++p) t[p] = X[(r0 + p) * 64 + lane];
        store8(&act[w][lane][0], t);
    }
    __syncthreads();
    float acc[8];
#pragma unroll
    for (int p = 0; p < 8; ++p) acc[p] = 0.f;
    for (int k = 0; k < 64; ++k) fma8(&act[w][k][0], W[k * 64 + lane], acc);
#pragma unroll
    for (int p = 0; p < 8; ++p) Y[(r0 + p) * 64 + lane] = (_Float16)acc[p];
}

// ---------------- CSR build ----------------
__global__ __launch_bounds__(256) void k_hist(const int* __restrict__ ind,
                                              int* __restrict__ cnt, int n) {
    int t = blockIdx.x * 256 + threadIdx.x;
    if (t < n) atomicAdd(&cnt[ind[2 * t]], 1);
}

__global__ __launch_bounds__(256) void k_scan1(const int* __restrict__ cnt,
                                               int* __restrict__ off,
                                               int* __restrict__ bsum, int n) {
    __shared__ int s[256];
    int b = blockIdx.x, t = threadIdx.x, a = b * 256 + t;
    int v = (a < n) ? cnt[a] : 0;
    s[t] = v;
    __syncthreads();
    for (int o = 1; o < 256; o <<= 1) {
        int x = (t >= o) ? s[t - o] : 0;
        __syncthreads();
        s[t] += x;
        __syncthreads();
    }
    off[a] = s[t] - v;
    if (t == 255) bsum[b] = s[255];
}

__global__ __launch_bounds__(64) void k_scan2(int* __restrict__ bsum, int nb) {
    if (threadIdx.x == 0) {
        int r = 0;
        for (int b = 0; b < nb; ++b) { int t = bsum[b]; bsum[b] = r; r += t; }
    }
}

__global__ __launch_bounds__(256) void k_scan3(int* __restrict__ off,
                                               const int* __restrict__ bsum) {
    int a = blockIdx.x * 256 + threadIdx.x;
    off[a] += bsum[blockIdx.x];
}

// scatter pair data directly into slot order (fused permute)
__global__ __launch_bounds__(256) void k_scatter(const int* __restrict__ ind,
                                                 const int* __restrict__ off,
                                                 int* __restrict__ fill,
                                                 const float* __restrict__ basis,
                                                 const float* __restrict__ diff,
                                                 int* __restrict__ iiS,
                                                 int* __restrict__ jjS,
                                                 float4* __restrict__ basS,
                                                 float4* __restrict__ difS, int n) {
    int t = blockIdx.x * 256 + threadIdx.x;
    if (t < n) {
        int i = ind[2 * t];
        int slot = off[i] + atomicAdd(&fill[i], 1);
        iiS[slot] = i;
        jjS[slot] = ind[2 * t + 1];
        basS[slot] = *(const float4*)(basis + 4 * t);
        difS[slot] = make_float4(diff[3 * t], diff[3 * t + 1], diff[3 * t + 2], 0.f);
    }
}

// ---------------- K3: CSR-ordered chain, 4 waves/block, NO barriers ----------------
__global__ __launch_bounds__(256) void k_pairs_s(
    const int* __restrict__ iiS, const int* __restrict__ jjS,
    const float4* __restrict__ basS, const float4* __restrict__ difS,
    const _Float16* __restrict__ p1h, const _Float16* __restrict__ p3h,
    const _Float16* __restrict__ wsA,
    const float* __restrict__ bpi1, const float* __restrict__ bpi2,
    float* __restrict__ outp1, float* __restrict__ outp3) {
    __shared__ float xpose[4][16][68];   // per-wave tile, no cross-wave sharing
    const int lane = threadIdx.x & 63;
    const int wv = threadIdx.x >> 6;
    const int p = lane & 15, q = lane >> 4;
    const int sbase = (blockIdx.x * 4 + wv) * 16;
    const int slot = sbase + p;
    const int ii = iiS[slot], jj = jjS[slot];

    const half8* A = (const half8*)wsA;

    // ---- pi1: K=128 (p1h_i | p1h_j), M=64, bias, tanh ----
    half8 b1[4];
    b1[0] = *(const half8*)(p1h + ii * 64 + q * 8);
    b1[1] = *(const half8*)(p1h + ii * 64 + 32 + q * 8);
    b1[2] = *(const half8*)(p1h + jj * 64 + q * 8);
    b1[3] = *(const half8*)(p1h + jj * 64 + 32 + q * 8);

    floatx4 h1[4];
#pragma unroll
    for (int mt = 0; mt < 4; ++mt) {
        floatx4 acc = *(const floatx4*)(bpi1 + 16 * mt + 4 * q);
#pragma unroll
        for (int kb = 0; kb < 4; ++kb)
            acc = MFMA16(A[(FB_PI1 + mt * 4 + kb) * 64 + lane], b1[kb], acc);
        h1[mt] = tanh4(acc);
    }

    // ---- pi2: K=64, M=256, bias, tanh, basis contraction ----
    half8 b2lo, b2hi;
    pack_can(h1, b2lo, b2hi);
    float4 bsv = basS[slot];
    float i1v[16];
#pragma unroll
    for (int mt = 0; mt < 16; ++mt) {
        floatx4 acc = *(const floatx4*)(bpi2 + 16 * mt + 4 * q);
        acc = MFMA16(A[(FB_PI2 + mt * 2 + 0) * 64 + lane], b2lo, acc);
        acc = MFMA16(A[(FB_PI2 + mt * 2 + 1) * 64 + lane], b2hi, acc);
        i1v[mt] = fast_tanh(acc[0]) * bsv.x + fast_tanh(acc[1]) * bsv.y +
                  fast_tanh(acc[2]) * bsv.z + fast_tanh(acc[3]) * bsv.w;
    }

    // ---- ii1: K=64 (sigma: k = 4*(8kb+e)+q), M=64, tanh ----
    half8 bi0, bi1;
    {
        half2t dw[8];
#pragma unroll
        for (int j = 0; j < 8; ++j)
            dw[j] = __builtin_amdgcn_cvt_pkrtz(i1v[2 * j], i1v[2 * j + 1]);
        union U { half8 v; half2t d[4]; } u;
        u.d[0] = dw[0]; u.d[1] = dw[1]; u.d[2] = dw[2]; u.d[3] = dw[3]; bi0 = u.v;
        u.d[0] = dw[4]; u.d[1] = dw[5]; u.d[2] = dw[6]; u.d[3] = dw[7]; bi1 = u.v;
    }
    floatx4 h3[4];
#pragma unroll
    for (int mt = 0; mt < 4; ++mt) {
        floatx4 acc = {0.f, 0.f, 0.f, 0.f};
        acc = MFMA16(A[(FB_II1 + mt * 2 + 0) * 64 + lane], bi0, acc);
        acc = MFMA16(A[(FB_II1 + mt * 2 + 1) * 64 + lane], bi1, acc);
        h3[mt] = tanh4(acc);
    }

    // ---- ii2: K=64, M=192, tanh; i1_1 / i1_2(->xpose) / i1_3 ----
    half8 b4lo, b4hi;
    pack_can(h3, b4lo, b4hi);
    floatx4 i11[4], i13[4];
#pragma unroll
    for (int mt = 0; mt < 12; ++mt) {
        floatx4 acc = {0.f, 0.f, 0.f, 0.f};
        acc = MFMA16(A[(FB_II2 + mt * 2 + 0) * 64 + lane], b4lo, acc);
        acc = MFMA16(A[(FB_II2 + mt * 2 + 1) * 64 + lane], b4hi, acc);
        floatx4 t = tanh4(acc);
        if (mt < 4) i11[mt] = t;
        else if (mt < 8) {
            int g = (mt - 4) * 4 + q;
            *(float4*)&xpose[wv][p][g * 4] = make_float4(t[0], t[1], t[2], t[3]);
        } else i13[mt - 8] = t;
    }

    // preload p3h fragments
    half8 bfi[3][2], bfj[3][2];
#pragma unroll
    for (int x = 0; x < 3; ++x) {
#pragma unroll
        for (int kb = 0; kb < 2; ++kb) {
            bfi[x][kb] = *(const half8*)(p3h + (ii * 3 + x) * 64 + kb * 32 + q * 8);
            bfj[x][kb] = *(const half8*)(p3h + (jj * 3 + x) * 64 + kb * 32 + q * 8);
        }
    }

    // ---- segmented flush of i1_2: one atomic row per distinct atom ----
    {
        float racc = xpose[wv][0][lane];
        int cur = iiS[sbase];
#pragma unroll
        for (int pp = 1; pp < 16; ++pp) {
            int aw = iiS[sbase + pp];          // wave-uniform
            if (aw != cur) {
                atomicAdd(&outp1[cur * 64 + lane], racc);
                racc = 0.f; cur = aw;
            }
            racc += xpose[wv][pp][lane];
        }
        atomicAdd(&outp1[cur * 64 + lane], racc);
    }

    // ---- i3 = p3h_i@Wpxi + p3h_j@Wpxj, scale, segmented flush per x ----
    float4 dv = difS[slot];
    float dvs[3] = {dv.x, dv.y, dv.z};
#pragma unroll
    for (int x = 0; x < 3; ++x) {
#pragma unroll
        for (int mt = 0; mt < 4; ++mt) {
            half8 ai0 = A[(FB_PXI + mt * 2 + 0) * 64 + lane];
            half8 ai1 = A[(FB_PXI + mt * 2 + 1) * 64 + lane];
            half8 aj0 = A[(FB_PXJ + mt * 2 + 0) * 64 + lane];
            half8 aj1 = A[(FB_PXJ + mt * 2 + 1) * 64 + lane];
            floatx4 acc = {0.f, 0.f, 0.f, 0.f};
            acc = MFMA16(ai0, bfi[x][0], acc);
            acc = MFMA16(ai1, bfi[x][1], acc);
            acc = MFMA16(aj0, bfj[x][0], acc);
            acc = MFMA16(aj1, bfj[x][1], acc);
            float4 v;
            v.x = fmaf(acc[0], i13[mt][0], dvs[x] * i11[mt][0]);
            v.y = fmaf(acc[1], i13[mt][1], dvs[x] * i11[mt][1]);
            v.z = fmaf(acc[2], i13[mt][2], dvs[x] * i11[mt][2]);
            v.w = fmaf(acc[3], i13[mt][3], dvs[x] * i11[mt][3]);
            *(float4*)&xpose[wv][p][(4 * mt + q) * 4] = v;
        }
        {
            float racc = xpose[wv][0][lane];
            int cur = iiS[sbase];
#pragma unroll
            for (int pp = 1; pp < 16; ++pp) {
                int aw = iiS[sbase + pp];
                if (aw != cur) {
                    atomicAdd(&outp3[cur * 192 + x * 64 + lane], racc);
                    racc = 0.f; cur = aw;
                }
                racc += xpose[wv][pp][lane];
            }
            atomicAdd(&outp3[cur * 192 + x * 64 + lane], racc);
        }
    }
}

// ---------------- K3b (fallback): round-4 coalesced-atomic path ----------------
__global__ __launch_bounds__(256) void k_pairs(
    const int* __restrict__ ind, const _Float16* __restrict__ p1h,
    const _Float16* __restrict__ p3h, const float* __restrict__ diff,
    const float* __restrict__ basis, const _Float16* __restrict__ wsA,
    const float* __restrict__ bpi1, const float* __restrict__ bpi2,
    float* __restrict__ outp1, float* __restrict__ outp3) {
    __shared__ float xpose[4][16][68];
    const int lane = threadIdx.x & 63;
    const int wv = threadIdx.x >> 6;
    const int p = lane & 15, q = lane >> 4;
    const int pbase0 = (blockIdx.x * 4 + wv) * 16;
    const int pair = pbase0 + p;
    const int ii = ind[2 * pair], jj = ind[2 * pair + 1];
    const half8* A = (const half8*)wsA;
    half8 b1[4];
    b1[0] = *(const half8*)(p1h + ii * 64 + q * 8);
    b1[1] = *(const half8*)(p1h + ii * 64 + 32 + q * 8);
    b1[2] = *(const half8*)(p1h + jj * 64 + q * 8);
    b1[3] = *(const half8*)(p1h + jj * 64 + 32 + q * 8);
    floatx4 h1[4];
#pragma unroll
    for (int mt = 0; mt < 4; ++mt) {
        floatx4 acc = *(const floatx4*)(bpi1 + 16 * mt + 4 * q);
#pragma unroll
        for (int kb = 0; kb < 4; ++kb)
            acc = MFMA16(A[(FB_PI1 + mt * 4 + kb) * 64 + lane], b1[kb], acc);
        h1[mt] = tanh4(acc);
    }
    half8 b2lo, b2hi;
    pack_can(h1, b2lo, b2hi);
    floatx4 bs = *(const floatx4*)(basis + pair * 4);
    float i1v[16];
#pragma unroll
    for (int mt = 0; mt < 16; ++mt) {
        floatx4 acc = *(const floatx4*)(bpi2 + 16 * mt + 4 * q);
        acc = MFMA16(A[(FB_PI2 + mt * 2 + 0) * 64 + lane], b2lo, acc);
        acc = MFMA16(A[(FB_PI2 + mt * 2 + 1) * 64 + lane], b2hi, acc);
        i1v[mt] = fast_tanh(acc[0]) * bs[0] + fast_tanh(acc[1]) * bs[1] +
                  fast_tanh(acc[2]) * bs[2] + fast_tanh(acc[3]) * bs[3];
    }
    half8 bi0, bi1;
    {
        half2t dw[8];
#pragma unroll
        for (int j = 0; j < 8; ++j)
            dw[j] = __builtin_amdgcn_cvt_pkrtz(i1v[2 * j], i1v[2 * j + 1]);
        union U { half8 v; half2t d[4]; } u;
        u.d[0] = dw[0]; u.d[1] = dw[1]; u.d[2] = dw[2]; u.d[3] = dw[3]; bi0 = u.v;
        u.d[0] = dw[4]; u.d[1] = dw[5]; u.d[2] = dw[6]; u.d[3] = dw[7]; bi1 = u.v;
    }
    floatx4 h3[4];
#pragma unroll
    for (int mt = 0; mt < 4; ++mt) {
        floatx4 acc = {0.f, 0.f, 0.f, 0.f};
        acc = MFMA16(A[(FB_II1 + mt * 2 + 0) * 64 + lane], bi0, acc);
        acc = MFMA16(A[(FB_II1 + mt * 2 + 1) * 64 + lane], bi1, acc);
        h3[mt] = tanh4(acc);
    }
    half8 b4lo, b4hi;
    pack_can(h3, b4lo, b4hi);
    floatx4 i11[4], i13[4];
#pragma unroll
    for (int mt = 0; mt < 12; ++mt) {
        floatx4 acc = {0.f, 0.f, 0.f, 0.f};
        acc = MFMA16(A[(FB_II2 + mt * 2 + 0) * 64 + lane], b4lo, acc);
        acc = MFMA16(A[(FB_II2 + mt * 2 + 1) * 64 + lane], b4hi, acc);
        floatx4 t = tanh4(acc);
        if (mt < 4) i11[mt] = t;
        else if (mt < 8) {
            int g = (mt - 4) * 4 + q;
            *(float4*)&xpose[wv][p][g * 4] = make_float4(t[0], t[1], t[2], t[3]);
        } else i13[mt - 8] = t;
    }
    half8 bfi[3][2], bfj[3][2];
#pragma unroll
    for (int x = 0; x < 3; ++x) {
#pragma unroll
        for (int kb = 0; kb < 2; ++kb) {
            bfi[x][kb] = *(const half8*)(p3h + (ii * 3 + x) * 64 + kb * 32 + q * 8);
            bfj[x][kb] = *(const half8*)(p3h + (jj * 3 + x) * 64 + kb * 32 + q * 8);
        }
    }
    __syncthreads();
#pragma unroll
    for (int pp = 0; pp < 16; ++pp) {
        int iw = ind[2 * (pbase0 + pp)];
        atomicAdd(&outp1[iw * 64 + lane], xpose[wv][pp][lane]);
    }
    __syncthreads();
    float dvs[3];
    dvs[0] = diff[pair * 3]; dvs[1] = diff[pair * 3 + 1]; dvs[2] = diff[pair * 3 + 2];
#pragma unroll
    for (int x = 0; x < 3; ++x) {
#pragma unroll
        for (int mt = 0; mt < 4; ++mt) {
            half8 ai0 = A[(FB_PXI + mt * 2 + 0) * 64 + lane];
            half8 ai1 = A[(FB_PXI + mt * 2 + 1) * 64 + lane];
            half8 aj0 = A[(FB_PXJ + mt * 2 + 0) * 64 + lane];
            half8 aj1 = A[(FB_PXJ + mt * 2 + 1) * 64 + lane];
            floatx4 acc = {0.f, 0.f, 0.f, 0.f};
            acc = MFMA16(ai0, bfi[x][0], acc);
            acc = MFMA16(ai1, bfi[x][1], acc);
            acc = MFMA16(aj0, bfj[x][0], acc);
            acc = MFMA16(aj1, bfj[x][1], acc);
            float4 v;
            v.x = fmaf(acc[0], i13[mt][0], dvs[x] * i11[mt][0]);
            v.y = fmaf(acc[1], i13[mt][1], dvs[x] * i11[mt][1]);
            v.z = fmaf(acc[2], i13[mt][2], dvs[x] * i11[mt][2]);
            v.w = fmaf(acc[3], i13[mt][3], dvs[x] * i11[mt][3]);
            *(float4*)&xpose[wv][p][(4 * mt + q) * 4] = v;
        }
        __syncthreads();
#pragma unroll
        for (int pp = 0; pp < 16; ++pp) {
            int iw = ind[2 * (pbase0 + pp)];
            atomicAdd(&outp3[iw * 192 + x * 64 + lane], xpose[wv][pp][lane]);
        }
        __syncthreads();
    }
}

// ---------------- K4: per-atom epilogue ----------------
__global__ __launch_bounds__(256) void k_final(const float* __restrict__ Wdi,
                                               const float* __restrict__ Wdj,
                                               float* __restrict__ outp1,
                                               float* __restrict__ outp3) {
    __shared__ float act[4][192][8];
    const int w = threadIdx.x >> 6, lane = threadIdx.x & 63;
    const int a0 = blockIdx.x * 32 + w * 8;
    for (int x = 0; x < 3; ++x) {
        float t[8];
#pragma unroll
        for (int p = 0; p < 8; ++p) t[p] = outp3[((a0 + p) * 3 + x) * 64 + lane];
        store8(&act[w][x * 64 + lane][0], t);
    }
    __syncthreads();
    float u0[8], u1[8], u2[8], v0[8], v1[8], v2[8];
#pragma unroll
    for (int p = 0; p < 8; ++p) {
        u0[p] = u1[p] = u2[p] = 0.f;
        v0[p] = v1[p] = v2[p] = 0.f;
    }
    for (int k = 0; k < 64; ++k) {
        float wi = Wdi[k * 64 + lane];
        float wj = Wdj[k * 64 + lane];
        fma8(&act[w][k][0], wi, u0);
        fma8(&act[w][64 + k][0], wi, u1);
        fma8(&act[w][128 + k][0], wi, u2);
        fma8(&act[w][k][0], wj, v0);
        fma8(&act[w][64 + k][0], wj, v1);
        fma8(&act[w][128 + k][0], wj, v2);
    }
#pragma unroll
    for (int p = 0; p < 8; ++p) {
        float dot = u0[p] * v0[p] + u1[p] * v1[p] + u2[p] * v2[p];
        int o1 = (a0 + p) * 64 + lane;
        float p1t = dot + outp1[o1];
        outp1[o1] = p1t;
#pragma unroll
        for (int x = 0; x < 3; ++x) {
            int o3 = ((a0 + p) * 3 + x) * 64 + lane;
            outp3[o3] = act[w][x * 64 + lane][p] * p1t;
        }
    }
}

extern "C" void kernel_launch(void* const* d_in, const int* in_sizes, int n_in,
                              void* d_out, int out_size, void* d_ws, size_t ws_size,
                              hipStream_t stream) {
    const int*   ind   = (const int*)d_in[0];
    const float* p1    = (const float*)d_in[1];
    const float* p3    = (const float*)d_in[2];
    const float* diff  = (const float*)d_in[3];
    const float* basis = (const float*)d_in[4];
    const float* Wpp1a = (const float*)d_in[5];
    const float* bpp1a = (const float*)d_in[6];
    const float* Wpp1b = (const float*)d_in[7];
    const float* bpp1b = (const float*)d_in[8];
    const float* Wpi1  = (const float*)d_in[9];
    const float* bpi1  = (const float*)d_in[10];
    const float* Wpi2  = (const float*)d_in[11];
    const float* bpi2  = (const float*)d_in[12];
    const float* Wii1  = (const float*)d_in[13];
    const float* Wii2  = (const float*)d_in[14];
    const float* Wpp3a = (const float*)d_in[15];
    const float* Wpp3b = (const float*)d_in[16];
    const float* Wpxi  = (const float*)d_in[17];
    const float* Wpxj  = (const float*)d_in[18];
    const float* Wdi   = (const float*)d_in[19];
    const float* Wdj   = (const float*)d_in[20];

    const int n_atoms = in_sizes[1] / 64;   // 20000
    const int n_pairs = in_sizes[0] / 2;    // 640000

    float* outp1 = (float*)d_out;
    float* outp3 = outp1 + (size_t)n_atoms * 64;

    char* ws = (char*)d_ws;
    _Float16* wsA  = (_Float16*)(ws + WSA_OFF);
    float*    W3   = (float*)(ws + W3_OFF);
    _Float16* p1h  = (_Float16*)(ws + P1H_OFF);
    _Float16* p3h  = (_Float16*)(ws + P3H_OFF);
    int*      cnt  = (int*)(ws + CNT_OFF);
    int*      fill = (int*)(ws + FILL_OFF);
    int*      offa = (int*)(ws + OFF_OFF);
    int*      bsum = (int*)(ws + BSUM_OFF);
    int*      iiS  = (int*)(ws + IIS_OFF);
    int*      jjS  = (int*)(ws + JJS_OFF);
    float4*   basS = (float4*)(ws + BAS_OFF);
    float4*   difS = (float4*)(ws + DIF_OFF);

    // shared prologue
    k_pack<<<96, 64, 0, stream>>>(Wpi1, Wpi2, Wii1, Wii2, Wpxi, Wpxj, wsA);
    k_w3<<<1, 256, 0, stream>>>(Wpp3a, Wpp3b, W3);
    k_p1h<<<n_atoms / 32, 256, 0, stream>>>(p1, Wpp1a, bpp1a, Wpp1b, bpp1b, p1h);
    k_rowmm<<<(n_atoms * 3) / 32, 256, 0, stream>>>(p3, W3, p3h);

    (void)hipMemsetAsync(d_out, 0, (size_t)out_size * sizeof(float), stream);

    if (ws_size >= 38757888) {  // fused CSR path
        const int nb = (n_atoms + 255) / 256;
        (void)hipMemsetAsync(ws + CNT_OFF, 0, 2 * 80896, stream);  // cnt + fill
        k_hist<<<(n_pairs + 255) / 256, 256, 0, stream>>>(ind, cnt, n_pairs);
        k_scan1<<<nb, 256, 0, stream>>>(cnt, offa, bsum, n_atoms);
        k_scan2<<<1, 64, 0, stream>>>(bsum, nb);
        k_scan3<<<nb, 256, 0, stream>>>(offa, bsum);
        k_scatter<<<(n_pairs + 255) / 256, 256, 0, stream>>>(ind, offa, fill, basis, diff,
                                                             iiS, jjS, basS, difS, n_pairs);
        k_pairs_s<<<n_pairs / 64, 256, 0, stream>>>(iiS, jjS, basS, difS, p1h, p3h,
                                                    wsA, bpi1, bpi2, outp1, outp3);
    } else {  // fallback: coalesced-atomic path
        k_pairs<<<n_pairs / 64, 256, 0, stream>>>(ind, p1h, p3h, diff, basis, wsA,
                                                  bpi1, bpi2, outp1, outp3);
    }

    k_final<<<n_atoms / 32, 256, 0, stream>>>(Wdi, Wdj, outp1, outp3);
}

// Round 11
// 499.875 us; speedup vs baseline: 1.1572x; 1.1572x over previous
//
#include <hip/hip_runtime.h>

// PiNet2 fused, MFMA f16 + CSR-ordered pairs, segmented flush, dual-group ILP.
// N_ATOMS=20000, N_PAIRS=640000, C=64, NB=4.
//
// k_pairs_s: ONE wave per block; each wave processes TWO independent groups
// of 16 CSR-consecutive pairs. Every stage is emitted as interleaved A/B
// instruction pairs sharing one weight fragment -> the two dependency
// chains hide each other's MFMA/tanh latency (TLP is capped at ~2 waves/
// SIMD per r9/r10 measurements, so latency hiding must come from ILP).
// Segment sums: run-length accumulate in LDS-transposed tiles + ~1.5
// atomicAdd rows per group. No __syncthreads anywhere in the hot kernel.
// Orientation: A = W^T (M=outch), B = activations^T (N=pairs).
// C/D layout (HW-verified): col = lane&15 (pair), row = (lane>>4)*4 + reg.
// Weights pre-packed (k_pack) fragment-linear with per-stage k-maps so all
// stage->stage handoffs are lane-local.

typedef _Float16 half8 __attribute__((ext_vector_type(8)));
typedef __fp16 half2t __attribute__((ext_vector_type(2)));   // cvt_pkrtz return type
typedef float floatx4 __attribute__((ext_vector_type(4)));

#define MFMA16(a, b, c) __builtin_amdgcn_mfma_f32_16x16x32_f16((a), (b), (c), 0, 0, 0)

// ws layout (bytes)
#define WSA_OFF 0            // 96 frags * 512 f16 * 2B = 98304
#define W3_OFF 98304
#define P1H_OFF 114688       // 20000*64 f16
#define P3H_OFF 2674688      // 20000*192 f16
#define CNT_OFF 10354688     // 20224 ints
#define FILL_OFF 10435584    // 20224 ints
#define OFF_OFF 10516480     // 20224 ints
#define BSUM_OFF 10597376    // 128 ints
#define IIS_OFF 13157888     // 640000 ints (atom i of slot)
#define JJS_OFF 15717888     // 640000 ints (atom j of slot)
#define BAS_OFF 18277888     // 640000 float4
#define DIF_OFF 28517888     // 640000 float4 (xyz + pad)  -> end 38757888

// frag-table bases (in frag units, 512 f16 each)
#define FB_PI1 0
#define FB_PI2 16
#define FB_II1 48
#define FB_II2 56
#define FB_PXI 80
#define FB_PXJ 88

__device__ __forceinline__ float fast_tanh(float x) {
    float t = __expf(2.0f * x);
    return 1.0f - __fdividef(2.0f, t + 1.0f);
}

__device__ __forceinline__ floatx4 tanh4(floatx4 v) {
    floatx4 r;
    r[0] = fast_tanh(v[0]); r[1] = fast_tanh(v[1]);
    r[2] = fast_tanh(v[2]); r[3] = fast_tanh(v[3]);
    return r;
}

__device__ __forceinline__ void pack_can(const floatx4 h[4], half8& lo, half8& hi) {
    half2t dw[8];
#pragma unroll
    for (int t = 0; t < 4; ++t) {
        dw[2 * t]     = __builtin_amdgcn_cvt_pkrtz(h[t][0], h[t][1]);
        dw[2 * t + 1] = __builtin_amdgcn_cvt_pkrtz(h[t][2], h[t][3]);
    }
    union U { half8 v; half2t d[4]; } u;
    u.d[0] = dw[0]; u.d[1] = dw[1]; u.d[2] = dw[2]; u.d[3] = dw[3]; lo = u.v;
    u.d[0] = dw[4]; u.d[1] = dw[5]; u.d[2] = dw[6]; u.d[3] = dw[7]; hi = u.v;
}

// ---------------- weight pre-pack ----------------
__global__ __launch_bounds__(64) void k_pack(
    const float* __restrict__ Wpi1, const float* __restrict__ Wpi2,
    const float* __restrict__ Wii1, const float* __restrict__ Wii2,
    const float* __restrict__ Wpxi, const float* __restrict__ Wpxj,
    _Float16* __restrict__ wsA) {
    int f = blockIdx.x, l = threadIdx.x;
    int q = l >> 4, c15 = l & 15;
    const float* W; int ldn, mt, kb, mode;
    if (f < 16)      { W = Wpi1; ldn = 64;  mt = f >> 2;        kb = f & 3;        mode = 0; }
    else if (f < 48) { W = Wpi2; ldn = 256; mt = (f - 16) >> 1; kb = (f - 16) & 1; mode = 1; }
    else if (f < 56) { W = Wii1; ldn = 64;  mt = (f - 48) >> 1; kb = (f - 48) & 1; mode = 2; }
    else if (f < 80) { W = Wii2; ldn = 192; mt = (f - 56) >> 1; kb = (f - 56) & 1; mode = 1; }
    else if (f < 88) { W = Wpxi; ldn = 64;  mt = (f - 80) >> 1; kb = (f - 80) & 1; mode = 0; }
    else             { W = Wpxj; ldn = 64;  mt = (f - 88) >> 1; kb = (f - 88) & 1; mode = 0; }
#pragma unroll
    for (int e = 0; e < 8; ++e) {
        int k;
        if (mode == 0) k = 32 * kb + 8 * q + e;
        else if (mode == 1) {
            int d = e >> 1, h = e & 1, j = 4 * kb + d;
            k = 16 * (j >> 1) + 4 * q + 2 * (j & 1) + h;
        } else k = 4 * (8 * kb + e) + q;
        wsA[f * 512 + l * 8 + e] = (_Float16)W[k * ldn + 16 * mt + c15];
    }
}

// ---------------- K0: W3 = Wpp3a @ Wpp3b ----------------
__global__ __launch_bounds__(256) void k_w3(const float* __restrict__ A,
                                            const float* __restrict__ B,
                                            float* __restrict__ W3) {
    int t = threadIdx.x;
#pragma unroll
    for (int e = 0; e < 16; ++e) {
        int idx = t * 16 + e;
        int k = idx >> 6, c = idx & 63;
        float s = 0.f;
        for (int m = 0; m < 64; ++m) s = fmaf(A[k * 64 + m], B[m * 64 + c], s);
        W3[idx] = s;
    }
}

__device__ __forceinline__ void store8(float* dst, const float v[8]) {
    *(float4*)(dst)     = make_float4(v[0], v[1], v[2], v[3]);
    *(float4*)(dst + 4) = make_float4(v[4], v[5], v[6], v[7]);
}
__device__ __forceinline__ void fma8(const float* row, float wv, float acc[8]) {
    float4 x0 = *(const float4*)(row);
    float4 x1 = *(const float4*)(row + 4);
    acc[0] = fmaf(x0.x, wv, acc[0]); acc[1] = fmaf(x0.y, wv, acc[1]);
    acc[2] = fmaf(x0.z, wv, acc[2]); acc[3] = fmaf(x0.w, wv, acc[3]);
    acc[4] = fmaf(x1.x, wv, acc[4]); acc[5] = fmaf(x1.y, wv, acc[5]);
    acc[6] = fmaf(x1.z, wv, acc[6]); acc[7] = fmaf(x1.w, wv, acc[7]);
}

// ---------------- K1: p1h (f16 out) ----------------
__global__ __launch_bounds__(256) void k_p1h(const float* __restrict__ p1,
                                             const float* __restrict__ Wa,
                                             const float* __restrict__ ba,
                                             const float* __restrict__ Wb,
                                             const float* __restrict__ bb,
                                             _Float16* __restrict__ p1h) {
    __shared__ float act[4][64][8];
    const int w = threadIdx.x >> 6, lane = threadIdx.x & 63;
    const int a0 = blockIdx.x * 32 + w * 8;
    {
        float t[8];
#pragma unroll
        for (int p = 0; p < 8; ++p) t[p] = p1[(a0 + p) * 64 + lane];
        store8(&act[w][lane][0], t);
    }
    __syncthreads();
    float acc[8];
    {
        float bv = ba[lane];
#pragma unroll
        for (int p = 0; p < 8; ++p) acc[p] = bv;
        for (int k = 0; k < 64; ++k) fma8(&act[w][k][0], Wa[k * 64 + lane], acc);
    }
    __syncthreads();
    {
        float t[8];
#pragma unroll
        for (int p = 0; p < 8; ++p) t[p] = fast_tanh(acc[p]);
        store8(&act[w][lane][0], t);
    }
    __syncthreads();
    {
        float bv = bb[lane];
#pragma unroll
        for (int p = 0; p < 8; ++p) acc[p] = bv;
        for (int k = 0; k < 64; ++k) fma8(&act[w][k][0], Wb[k * 64 + lane], acc);
    }
#pragma unroll
    for (int p = 0; p < 8; ++p) p1h[(a0 + p) * 64 + lane] = (_Float16)fast_tanh(acc[p]);
}

// ---------------- K2: p3h = p3 @ W3 (f16 out) ----------------
__global__ __launch_bounds__(256) void k_rowmm(const float* __restrict__ X,
                                               const float* __restrict__ W,
                                               _Float16* __restrict__ Y) {
    __shared__ float act[4][64][8];
    const int w = threadIdx.x >> 6, lane = threadIdx.x & 63;
    const int r0 = blockIdx.x * 32 + w * 8;
    {
        float t[8];
#pragma unroll
        for (int p = 0; p < 8; ++p) t[p] = X[(r0 + p) * 64 + lane];
        store8(&act[w][lane][0], t);
    }
    __syncthreads();
    float acc[8];
#pragma unroll
    for (int p = 0; p < 8; ++p) acc[p] = 0.f;
    for (int k = 0; k < 64; ++k) fma8(&act[w][k][0], W[k * 64 + lane], acc);
#pragma unroll
    for (int p = 0; p < 8; ++p) Y[(r0 + p) * 64 + lane] = (_Float16)acc[p];
}

// ---------------- CSR build ----------------
__global__ __launch_bounds__(256) void k_hist(const int* __restrict__ ind,
                                              int* __restrict__ cnt, int n) {
    int t = blockIdx.x * 256 + threadIdx.x;
    if (t < n) atomicAdd(&cnt[ind[2 * t]], 1);
}

__global__ __launch_bounds__(256) void k_scan1(const int* __restrict__ cnt,
                                               int* __restrict__ off,
                                               int* __restrict__ bsum, int n) {
    __shared__ int s[256];
    int b = blockIdx.x, t = threadIdx.x, a = b * 256 + t;
    int v = (a < n) ? cnt[a] : 0;
    s[t] = v;
    __syncthreads();
    for (int o = 1; o < 256; o <<= 1) {
        int x = (t >= o) ? s[t - o] : 0;
        __syncthreads();
        s[t] += x;
        __syncthreads();
    }
    off[a] = s[t] - v;
    if (t == 255) bsum[b] = s[255];
}

__global__ __launch_bounds__(64) void k_scan2(int* __restrict__ bsum, int nb) {
    if (threadIdx.x == 0) {
        int r = 0;
        for (int b = 0; b < nb; ++b) { int t = bsum[b]; bsum[b] = r; r += t; }
    }
}

__global__ __launch_bounds__(256) void k_scan3(int* __restrict__ off,
                                               const int* __restrict__ bsum) {
    int a = blockIdx.x * 256 + threadIdx.x;
    off[a] += bsum[blockIdx.x];
}

// scatter pair data directly into slot order (fused permute)
__global__ __launch_bounds__(256) void k_scatter(const int* __restrict__ ind,
                                                 const int* __restrict__ off,
                                                 int* __restrict__ fill,
                                                 const float* __restrict__ basis,
                                                 const float* __restrict__ diff,
                                                 int* __restrict__ iiS,
                                                 int* __restrict__ jjS,
                                                 float4* __restrict__ basS,
                                                 float4* __restrict__ difS, int n) {
    int t = blockIdx.x * 256 + threadIdx.x;
    if (t < n) {
        int i = ind[2 * t];
        int slot = off[i] + atomicAdd(&fill[i], 1);
        iiS[slot] = i;
        jjS[slot] = ind[2 * t + 1];
        basS[slot] = *(const float4*)(basis + 4 * t);
        difS[slot] = make_float4(diff[3 * t], diff[3 * t + 1], diff[3 * t + 2], 0.f);
    }
}

// ---------------- K3: CSR-ordered chain, 1 wave/block, 2 groups/wave ----------------
__global__ __launch_bounds__(64) void k_pairs_s(
    const int* __restrict__ iiS, const int* __restrict__ jjS,
    const float4* __restrict__ basS, const float4* __restrict__ difS,
    const _Float16* __restrict__ p1h, const _Float16* __restrict__ p3h,
    const _Float16* __restrict__ wsA,
    const float* __restrict__ bpi1, const float* __restrict__ bpi2,
    float* __restrict__ outp1, float* __restrict__ outp3) {
    __shared__ float xpose[2][16][68];
    const int lane = threadIdx.x;
    const int p = lane & 15, q = lane >> 4;
    const int sb0 = blockIdx.x * 32;          // group g covers slots sb0+16g..+15
    const int slot0 = sb0 + p, slot1 = sb0 + 16 + p;
    const int iA0 = iiS[slot0], jA0 = jjS[slot0];
    const int iA1 = iiS[slot1], jA1 = jjS[slot1];

    const half8* A = (const half8*)wsA;

    // ---- gathers for both groups ----
    half8 b1[2][4];
    b1[0][0] = *(const half8*)(p1h + iA0 * 64 + q * 8);
    b1[0][1] = *(const half8*)(p1h + iA0 * 64 + 32 + q * 8);
    b1[0][2] = *(const half8*)(p1h + jA0 * 64 + q * 8);
    b1[0][3] = *(const half8*)(p1h + jA0 * 64 + 32 + q * 8);
    b1[1][0] = *(const half8*)(p1h + iA1 * 64 + q * 8);
    b1[1][1] = *(const half8*)(p1h + iA1 * 64 + 32 + q * 8);
    b1[1][2] = *(const half8*)(p1h + jA1 * 64 + q * 8);
    b1[1][3] = *(const half8*)(p1h + jA1 * 64 + 32 + q * 8);

    // ---- pi1: K=128, M=64, bias, tanh (A/B interleaved, shared weights) ----
    floatx4 h1[2][4];
#pragma unroll
    for (int mt = 0; mt < 4; ++mt) {
        floatx4 acc0 = *(const floatx4*)(bpi1 + 16 * mt + 4 * q);
        floatx4 acc1 = acc0;
#pragma unroll
        for (int kb = 0; kb < 4; ++kb) {
            half8 aw = A[(FB_PI1 + mt * 4 + kb) * 64 + lane];
            acc0 = MFMA16(aw, b1[0][kb], acc0);
            acc1 = MFMA16(aw, b1[1][kb], acc1);
        }
        h1[0][mt] = tanh4(acc0);
        h1[1][mt] = tanh4(acc1);
    }

    // ---- pi2: K=64, M=256, bias, tanh, basis contraction ----
    half8 b2lo[2], b2hi[2];
    pack_can(h1[0], b2lo[0], b2hi[0]);
    pack_can(h1[1], b2lo[1], b2hi[1]);
    float4 bsv0 = basS[slot0], bsv1 = basS[slot1];
    float i1v[2][16];
#pragma unroll
    for (int mt = 0; mt < 16; ++mt) {
        half8 a0 = A[(FB_PI2 + mt * 2 + 0) * 64 + lane];
        half8 a1 = A[(FB_PI2 + mt * 2 + 1) * 64 + lane];
        floatx4 acc0 = *(const floatx4*)(bpi2 + 16 * mt + 4 * q);
        floatx4 acc1 = acc0;
        acc0 = MFMA16(a0, b2lo[0], acc0);
        acc1 = MFMA16(a0, b2lo[1], acc1);
        acc0 = MFMA16(a1, b2hi[0], acc0);
        acc1 = MFMA16(a1, b2hi[1], acc1);
        i1v[0][mt] = fast_tanh(acc0[0]) * bsv0.x + fast_tanh(acc0[1]) * bsv0.y +
                     fast_tanh(acc0[2]) * bsv0.z + fast_tanh(acc0[3]) * bsv0.w;
        i1v[1][mt] = fast_tanh(acc1[0]) * bsv1.x + fast_tanh(acc1[1]) * bsv1.y +
                     fast_tanh(acc1[2]) * bsv1.z + fast_tanh(acc1[3]) * bsv1.w;
    }

    // ---- ii1: K=64 (sigma: k = 4*(8kb+e)+q), M=64, tanh ----
    half8 bi[2][2];
#pragma unroll
    for (int g = 0; g < 2; ++g) {
        half2t dw[8];
#pragma unroll
        for (int j = 0; j < 8; ++j)
            dw[j] = __builtin_amdgcn_cvt_pkrtz(i1v[g][2 * j], i1v[g][2 * j + 1]);
        union U { half8 v; half2t d[4]; } u;
        u.d[0] = dw[0]; u.d[1] = dw[1]; u.d[2] = dw[2]; u.d[3] = dw[3]; bi[g][0] = u.v;
        u.d[0] = dw[4]; u.d[1] = dw[5]; u.d[2] = dw[6]; u.d[3] = dw[7]; bi[g][1] = u.v;
    }
    floatx4 h3[2][4];
#pragma unroll
    for (int mt = 0; mt < 4; ++mt) {
        half8 a0 = A[(FB_II1 + mt * 2 + 0) * 64 + lane];
        half8 a1 = A[(FB_II1 + mt * 2 + 1) * 64 + lane];
        floatx4 acc0 = {0.f, 0.f, 0.f, 0.f};
        floatx4 acc1 = {0.f, 0.f, 0.f, 0.f};
        acc0 = MFMA16(a0, bi[0][0], acc0);
        acc1 = MFMA16(a0, bi[1][0], acc1);
        acc0 = MFMA16(a1, bi[0][1], acc0);
        acc1 = MFMA16(a1, bi[1][1], acc1);
        h3[0][mt] = tanh4(acc0);
        h3[1][mt] = tanh4(acc1);
    }

    // ---- ii2: K=64, M=192, tanh; i1_1 / i1_2(->xpose) / i1_3 ----
    half8 b4lo[2], b4hi[2];
    pack_can(h3[0], b4lo[0], b4hi[0]);
    pack_can(h3[1], b4lo[1], b4hi[1]);
    floatx4 i11v[2][4], i13v[2][4];
#pragma unroll
    for (int mt = 0; mt < 12; ++mt) {
        half8 a0 = A[(FB_II2 + mt * 2 + 0) * 64 + lane];
        half8 a1 = A[(FB_II2 + mt * 2 + 1) * 64 + lane];
        floatx4 acc0 = {0.f, 0.f, 0.f, 0.f};
        floatx4 acc1 = {0.f, 0.f, 0.f, 0.f};
        acc0 = MFMA16(a0, b4lo[0], acc0);
        acc1 = MFMA16(a0, b4lo[1], acc1);
        acc0 = MFMA16(a1, b4hi[0], acc0);
        acc1 = MFMA16(a1, b4hi[1], acc1);
        floatx4 t0 = tanh4(acc0);
        floatx4 t1 = tanh4(acc1);
        if (mt < 4) { i11v[0][mt] = t0; i11v[1][mt] = t1; }
        else if (mt < 8) {
            int g4 = ((mt - 4) * 4 + q) * 4;
            *(float4*)&xpose[0][p][g4] = make_float4(t0[0], t0[1], t0[2], t0[3]);
            *(float4*)&xpose[1][p][g4] = make_float4(t1[0], t1[1], t1[2], t1[3]);
        } else { i13v[0][mt - 8] = t0; i13v[1][mt - 8] = t1; }
    }

    // ---- segmented flush of i1_2 (both groups) ----
#pragma unroll
    for (int g = 0; g < 2; ++g) {
        float racc = xpose[g][0][lane];
        int cur = iiS[sb0 + g * 16];
#pragma unroll
        for (int pp = 1; pp < 16; ++pp) {
            int aw = iiS[sb0 + g * 16 + pp];   // wave-uniform
            if (aw != cur) {
                atomicAdd(&outp1[cur * 64 + lane], racc);
                racc = 0.f; cur = aw;
            }
            racc += xpose[g][pp][lane];
        }
        atomicAdd(&outp1[cur * 64 + lane], racc);
    }

    // ---- i3 = p3h_i@Wpxi + p3h_j@Wpxj, scale, segmented flush per x ----
    float4 dv0 = difS[slot0], dv1 = difS[slot1];
    float dvs[2][3] = {{dv0.x, dv0.y, dv0.z}, {dv1.x, dv1.y, dv1.z}};
#pragma unroll
    for (int x = 0; x < 3; ++x) {
        half8 bfi[2][2], bfj[2][2];
#pragma unroll
        for (int kb = 0; kb < 2; ++kb) {
            bfi[0][kb] = *(const half8*)(p3h + (iA0 * 3 + x) * 64 + kb * 32 + q * 8);
            bfj[0][kb] = *(const half8*)(p3h + (jA0 * 3 + x) * 64 + kb * 32 + q * 8);
            bfi[1][kb] = *(const half8*)(p3h + (iA1 * 3 + x) * 64 + kb * 32 + q * 8);
            bfj[1][kb] = *(const half8*)(p3h + (jA1 * 3 + x) * 64 + kb * 32 + q * 8);
        }
#pragma unroll
        for (int mt = 0; mt < 4; ++mt) {
            half8 ai0 = A[(FB_PXI + mt * 2 + 0) * 64 + lane];
            half8 ai1 = A[(FB_PXI + mt * 2 + 1) * 64 + lane];
            half8 aj0 = A[(FB_PXJ + mt * 2 + 0) * 64 + lane];
            half8 aj1 = A[(FB_PXJ + mt * 2 + 1) * 64 + lane];
            floatx4 acc0 = {0.f, 0.f, 0.f, 0.f};
            floatx4 acc1 = {0.f, 0.f, 0.f, 0.f};
            acc0 = MFMA16(ai0, bfi[0][0], acc0);
            acc1 = MFMA16(ai0, bfi[1][0], acc1);
            acc0 = MFMA16(ai1, bfi[0][1], acc0);
            acc1 = MFMA16(ai1, bfi[1][1], acc1);
            acc0 = MFMA16(aj0, bfj[0][0], acc0);
            acc1 = MFMA16(aj0, bfj[1][0], acc1);
            acc0 = MFMA16(aj1, bfj[0][1], acc0);
            acc1 = MFMA16(aj1, bfj[1][1], acc1);
            float4 v0, v1;
            v0.x = fmaf(acc0[0], i13v[0][mt][0], dvs[0][x] * i11v[0][mt][0]);
            v0.y = fmaf(acc0[1], i13v[0][mt][1], dvs[0][x] * i11v[0][mt][1]);
            v0.z = fmaf(acc0[2], i13v[0][mt][2], dvs[0][x] * i11v[0][mt][2]);
            v0.w = fmaf(acc0[3], i13v[0][mt][3], dvs[0][x] * i11v[0][mt][3]);
            v1.x = fmaf(acc1[0], i13v[1][mt][0], dvs[1][x] * i11v[1][mt][0]);
            v1.y = fmaf(acc1[1], i13v[1][mt][1], dvs[1][x] * i11v[1][mt][1]);
            v1.z = fmaf(acc1[2], i13v[1][mt][2], dvs[1][x] * i11v[1][mt][2]);
            v1.w = fmaf(acc1[3], i13v[1][mt][3], dvs[1][x] * i11v[1][mt][3]);
            int g4 = (4 * mt + q) * 4;
            *(float4*)&xpose[0][p][g4] = v0;
            *(float4*)&xpose[1][p][g4] = v1;
        }
#pragma unroll
        for (int g = 0; g < 2; ++g) {
            float racc = xpose[g][0][lane];
            int cur = iiS[sb0 + g * 16];
#pragma unroll
            for (int pp = 1; pp < 16; ++pp) {
                int aw = iiS[sb0 + g * 16 + pp];
                if (aw != cur) {
                    atomicAdd(&outp3[cur * 192 + x * 64 + lane], racc);
                    racc = 0.f; cur = aw;
                }
                racc += xpose[g][pp][lane];
            }
            atomicAdd(&outp3[cur * 192 + x * 64 + lane], racc);
        }
    }
}

// ---------------- K3b (fallback): round-4 coalesced-atomic path ----------------
__global__ __launch_bounds__(256) void k_pairs(
    const int* __restrict__ ind, const _Float16* __restrict__ p1h,
    const _Float16* __restrict__ p3h, const float* __restrict__ diff,
    const float* __restrict__ basis, const _Float16* __restrict__ wsA,
    const float* __restrict__ bpi1, const float* __restrict__ bpi2,
    float* __restrict__ outp1, float* __restrict__ outp3) {
    __shared__ float xpose[4][16][68];
    const int lane = threadIdx.x & 63;
    const int wv = threadIdx.x >> 6;
    const int p = lane & 15, q = lane >> 4;
    const int pbase0 = (blockIdx.x * 4 + wv) * 16;
    const int pair = pbase0 + p;
    const int ii = ind[2 * pair], jj = ind[2 * pair + 1];
    const half8* A = (const half8*)wsA;
    half8 b1[4];
    b1[0] = *(const half8*)(p1h + ii * 64 + q * 8);
    b1[1] = *(const half8*)(p1h + ii * 64 + 32 + q * 8);
    b1[2] = *(const half8*)(p1h + jj * 64 + q * 8);
    b1[3] = *(const half8*)(p1h + jj * 64 + 32 + q * 8);
    floatx4 h1[4];
#pragma unroll
    for (int mt = 0; mt < 4; ++mt) {
        floatx4 acc = *(const floatx4*)(bpi1 + 16 * mt + 4 * q);
#pragma unroll
        for (int kb = 0; kb < 4; ++kb)
            acc = MFMA16(A[(FB_PI1 + mt * 4 + kb) * 64 + lane], b1[kb], acc);
        h1[mt] = tanh4(acc);
    }
    half8 b2lo, b2hi;
    pack_can(h1, b2lo, b2hi);
    floatx4 bs = *(const floatx4*)(basis + pair * 4);
    float i1v[16];
#pragma unroll
    for (int mt = 0; mt < 16; ++mt) {
        floatx4 acc = *(const floatx4*)(bpi2 + 16 * mt + 4 * q);
        acc = MFMA16(A[(FB_PI2 + mt * 2 + 0) * 64 + lane], b2lo, acc);
        acc = MFMA16(A[(FB_PI2 + mt * 2 + 1) * 64 + lane], b2hi, acc);
        i1v[mt] = fast_tanh(acc[0]) * bs[0] + fast_tanh(acc[1]) * bs[1] +
                  fast_tanh(acc[2]) * bs[2] + fast_tanh(acc[3]) * bs[3];
    }
    half8 bi0, bi1;
    {
        half2t dw[8];
#pragma unroll
        for (int j = 0; j < 8; ++j)
            dw[j] = __builtin_amdgcn_cvt_pkrtz(i1v[2 * j], i1v[2 * j + 1]);
        union U { half8 v; half2t d[4]; } u;
        u.d[0] = dw[0]; u.d[1] = dw[1]; u.d[2] = dw[2]; u.d[3] = dw[3]; bi0 = u.v;
        u.d[0] = dw[4]; u.d[1] = dw[5]; u.d[2] = dw[6]; u.d[3] = dw[7]; bi1 = u.v;
    }
    floatx4 h3[4];
#pragma unroll
    for (int mt = 0; mt < 4; ++mt) {
        floatx4 acc = {0.f, 0.f, 0.f, 0.f};
        acc = MFMA16(A[(FB_II1 + mt * 2 + 0) * 64 + lane], bi0, acc);
        acc = MFMA16(A[(FB_II1 + mt * 2 + 1) * 64 + lane], bi1, acc);
        h3[mt] = tanh4(acc);
    }
    half8 b4lo, b4hi;
    pack_can(h3, b4lo, b4hi);
    floatx4 i11[4], i13[4];
#pragma unroll
    for (int mt = 0; mt < 12; ++mt) {
        floatx4 acc = {0.f, 0.f, 0.f, 0.f};
        acc = MFMA16(A[(FB_II2 + mt * 2 + 0) * 64 + lane], b4lo, acc);
        acc = MFMA16(A[(FB_II2 + mt * 2 + 1) * 64 + lane], b4hi, acc);
        floatx4 t = tanh4(acc);
        if (mt < 4) i11[mt] = t;
        else if (mt < 8) {
            int g = (mt - 4) * 4 + q;
            *(float4*)&xpose[wv][p][g * 4] = make_float4(t[0], t[1], t[2], t[3]);
        } else i13[mt - 8] = t;
    }
    half8 bfi[3][2], bfj[3][2];
#pragma unroll
    for (int x = 0; x < 3; ++x) {
#pragma unroll
        for (int kb = 0; kb < 2; ++kb) {
            bfi[x][kb] = *(const half8*)(p3h + (ii * 3 + x) * 64 + kb * 32 + q * 8);
            bfj[x][kb] = *(const half8*)(p3h + (jj * 3 + x) * 64 + kb * 32 + q * 8);
        }
    }
    __syncthreads();
#pragma unroll
    for (int pp = 0; pp < 16; ++pp) {
        int iw = ind[2 * (pbase0 + pp)];
        atomicAdd(&outp1[iw * 64 + lane], xpose[wv][pp][lane]);
    }
    __syncthreads();
    float dvs[3];
    dvs[0] = diff[pair * 3]; dvs[1] = diff[pair * 3 + 1]; dvs[2] = diff[pair * 3 + 2];
#pragma unroll
    for (int x = 0; x < 3; ++x) {
#pragma unroll
        for (int mt = 0; mt < 4; ++mt) {
            half8 ai0 = A[(FB_PXI + mt * 2 + 0) * 64 + lane];
            half8 ai1 = A[(FB_PXI + mt * 2 + 1) * 64 + lane];
            half8 aj0 = A[(FB_PXJ + mt * 2 + 0) * 64 + lane];
            half8 aj1 = A[(FB_PXJ + mt * 2 + 1) * 64 + lane];
            floatx4 acc = {0.f, 0.f, 0.f, 0.f};
            acc = MFMA16(ai0, bfi[x][0], acc);
            acc = MFMA16(ai1, bfi[x][1], acc);
            acc = MFMA16(aj0, bfj[x][0], acc);
            acc = MFMA16(aj1, bfj[x][1], acc);
            float4 v;
            v.x = fmaf(acc[0], i13[mt][0], dvs[x] * i11[mt][0]);
            v.y = fmaf(acc[1], i13[mt][1], dvs[x] * i11[mt][1]);
            v.z = fmaf(acc[2], i13[mt][2], dvs[x] * i11[mt][2]);
            v.w = fmaf(acc[3], i13[mt][3], dvs[x] * i11[mt][3]);
            *(float4*)&xpose[wv][p][(4 * mt + q) * 4] = v;
        }
        __syncthreads();
#pragma unroll
        for (int pp = 0; pp < 16; ++pp) {
            int iw = ind[2 * (pbase0 + pp)];
            atomicAdd(&outp3[iw * 192 + x * 64 + lane], xpose[wv][pp][lane]);
        }
        __syncthreads();
    }
}

// ---------------- K4: per-atom epilogue ----------------
__global__ __launch_bounds__(256) void k_final(const float* __restrict__ Wdi,
                                               const float* __restrict__ Wdj,
                                               float* __restrict__ outp1,
                                               float* __restrict__ outp3) {
    __shared__ float act[4][192][8];
    const int w = threadIdx.x >> 6, lane = threadIdx.x & 63;
    const int a0 = blockIdx.x * 32 + w * 8;
    for (int x = 0; x < 3; ++x) {
        float t[8];
#pragma unroll
        for (int p = 0; p < 8; ++p) t[p] = outp3[((a0 + p) * 3 + x) * 64 + lane];
        store8(&act[w][x * 64 + lane][0], t);
    }
    __syncthreads();
    float u0[8], u1[8], u2[8], v0[8], v1[8], v2[8];
#pragma unroll
    for (int p = 0; p < 8; ++p) {
        u0[p] = u1[p] = u2[p] = 0.f;
        v0[p] = v1[p] = v2[p] = 0.f;
    }
    for (int k = 0; k < 64; ++k) {
        float wi = Wdi[k * 64 + lane];
        float wj = Wdj[k * 64 + lane];
        fma8(&act[w][k][0], wi, u0);
        fma8(&act[w][64 + k][0], wi, u1);
        fma8(&act[w][128 + k][0], wi, u2);
        fma8(&act[w][k][0], wj, v0);
        fma8(&act[w][64 + k][0], wj, v1);
        fma8(&act[w][128 + k][0], wj, v2);
    }
#pragma unroll
    for (int p = 0; p < 8; ++p) {
        float dot = u0[p] * v0[p] + u1[p] * v1[p] + u2[p] * v2[p];
        int o1 = (a0 + p) * 64 + lane;
        float p1t = dot + outp1[o1];
        outp1[o1] = p1t;
#pragma unroll
        for (int x = 0; x < 3; ++x) {
            int o3 = ((a0 + p) * 3 + x) * 64 + lane;
            outp3[o3] = act[w][x * 64 + lane][p] * p1t;
        }
    }
}

extern "C" void kernel_launch(void* const* d_in, const int* in_sizes, int n_in,
                              void* d_out, int out_size, void* d_ws, size_t ws_size,
                              hipStream_t stream) {
    const int*   ind   = (const int*)d_in[0];
    const float* p1    = (const float*)d_in[1];
    const float* p3    = (const float*)d_in[2];
    const float* diff  = (const float*)d_in[3];
    const float* basis = (const float*)d_in[4];
    const float* Wpp1a = (const float*)d_in[5];
    const float* bpp1a = (const float*)d_in[6];
    const float* Wpp1b = (const float*)d_in[7];
    const float* bpp1b = (const float*)d_in[8];
    const float* Wpi1  = (const float*)d_in[9];
    const float* bpi1  = (const float*)d_in[10];
    const float* Wpi2  = (const float*)d_in[11];
    const float* bpi2  = (const float*)d_in[12];
    const float* Wii1  = (const float*)d_in[13];
    const float* Wii2  = (const float*)d_in[14];
    const float* Wpp3a = (const float*)d_in[15];
    const float* Wpp3b = (const float*)d_in[16];
    const float* Wpxi  = (const float*)d_in[17];
    const float* Wpxj  = (const float*)d_in[18];
    const float* Wdi   = (const float*)d_in[19];
    const float* Wdj   = (const float*)d_in[20];

    const int n_atoms = in_sizes[1] / 64;   // 20000
    const int n_pairs = in_sizes[0] / 2;    // 640000

    float* outp1 = (float*)d_out;
    float* outp3 = outp1 + (size_t)n_atoms * 64;

    char* ws = (char*)d_ws;
    _Float16* wsA  = (_Float16*)(ws + WSA_OFF);
    float*    W3   = (float*)(ws + W3_OFF);
    _Float16* p1h  = (_Float16*)(ws + P1H_OFF);
    _Float16* p3h  = (_Float16*)(ws + P3H_OFF);
    int*      cnt  = (int*)(ws + CNT_OFF);
    int*      fill = (int*)(ws + FILL_OFF);
    int*      offa = (int*)(ws + OFF_OFF);
    int*      bsum = (int*)(ws + BSUM_OFF);
    int*      iiS  = (int*)(ws + IIS_OFF);
    int*      jjS  = (int*)(ws + JJS_OFF);
    float4*   basS = (float4*)(ws + BAS_OFF);
    float4*   difS = (float4*)(ws + DIF_OFF);

    // shared prologue
    k_pack<<<96, 64, 0, stream>>>(Wpi1, Wpi2, Wii1, Wii2, Wpxi, Wpxj, wsA);
    k_w3<<<1, 256, 0, stream>>>(Wpp3a, Wpp3b, W3);
    k_p1h<<<n_atoms / 32, 256, 0, stream>>>(p1, Wpp1a, bpp1a, Wpp1b, bpp1b, p1h);
    k_rowmm<<<(n_atoms * 3) / 32, 256, 0, stream>>>(p3, W3, p3h);

    (void)hipMemsetAsync(d_out, 0, (size_t)out_size * sizeof(float), stream);

    if (ws_size >= 38757888) {  // fused CSR path
        const int nb = (n_atoms + 255) / 256;
        (void)hipMemsetAsync(ws + CNT_OFF, 0, 2 * 80896, stream);  // cnt + fill
        k_hist<<<(n_pairs + 255) / 256, 256, 0, stream>>>(ind, cnt, n_pairs);
        k_scan1<<<nb, 256, 0, stream>>>(cnt, offa, bsum, n_atoms);
        k_scan2<<<1, 64, 0, stream>>>(bsum, nb);
        k_scan3<<<nb, 256, 0, stream>>>(offa, bsum);
        k_scatter<<<(n_pairs + 255) / 256, 256, 0, stream>>>(ind, offa, fill, basis, diff,
                                                             iiS, jjS, basS, difS, n_pairs);
        k_pairs_s<<<n_pairs / 32, 64, 0, stream>>>(iiS, jjS, basS, difS, p1h, p3h,
                                                   wsA, bpi1, bpi2, outp1, outp3);
    } else {  // fallback: coalesced-atomic path
        k_pairs<<<n_pairs / 64, 256, 0, stream>>>(ind, p1h, p3h, diff, basis, wsA,
                                                  bpi1, bpi2, outp1, outp3);
    }

    k_final<<<n_atoms / 32, 256, 0, stream>>>(Wdi, Wdj, outp1, outp3);
}